// Round 3
// baseline (695.800 us; speedup 1.0000x reference)
//
#include <hip/hip_runtime.h>

#define CIN  16
#define COUT 16
#define SNUM 4
#define PPT  2    // points (n) per thread
#define TPB  256  // threads per block

// out[b,o,n] = sum_i W[o,i,s(b,n)] * x[b,i,n] + bias[o]
// Memory-bound: ~530 MB mandatory traffic. Key constraints:
//  - VGPR <= 128 so 16 waves/CU can overlap the HBM stream with the LDS
//    weight-read pipe (R1: 256 VGPR -> 3 waves/CU -> 2.2 TB/s only).
//  - LDS weight layout [i][ko][s] as float4: lane-varying address component
//    is only s*16 B -> <=4 distinct addresses/wave -> conflict-free (R1: 0).
__global__ __launch_bounds__(TPB, 4) void apr_conv1x1_kernel(
    const float* __restrict__ x,      // [B, CIN, N]
    const float* __restrict__ w,      // [COUT, CIN, SNUM]
    const float* __restrict__ bias,   // [COUT]
    const int*   __restrict__ sidx,   // [B, N]
    float*       __restrict__ out,    // [B, COUT, N]
    int N)
{
    __shared__ float4 w4[CIN * 4 * SNUM];   // 256 float4 = 4 KiB

    const int t = threadIdx.x;
    {
        // thread t owns float4 index t:  f = t*4 + j = i*64 + ko*16 + s*4 + j
        const int s  = t & 3;
        const int ko = (t >> 2) & 3;
        const int i  = t >> 4;
        float4 v;
        v.x = w[((ko * 4 + 0) * CIN + i) * SNUM + s];
        v.y = w[((ko * 4 + 1) * CIN + i) * SNUM + s];
        v.z = w[((ko * 4 + 2) * CIN + i) * SNUM + s];
        v.w = w[((ko * 4 + 3) * CIN + i) * SNUM + s];
        w4[t] = v;
    }
    __syncthreads();

    const unsigned tid  = blockIdx.x * TPB + t;
    const unsigned tpb_ = (unsigned)(N >> 1);         // threads per batch (PPT=2)
    const unsigned b    = (tid >= tpb_) ? 1u : 0u;    // B == 2: compare, no div
    const unsigned n    = (tid - b * tpb_) << 1;      // first of 2 consecutive n

    const float* xb = x   + (size_t)b * CIN  * N + n;
    float*       ob = out + (size_t)b * COUT * N + n;
    const int2 sv = *(const int2*)(sidx + (size_t)b * N + n);
    const int sb0 = sv.x, sb1 = sv.y;

    float acc[PPT][COUT];
    #pragma unroll
    for (int o = 0; o < COUT; ++o) {
        const float bv = bias[o];   // uniform address -> scalar load
        acc[0][o] = bv; acc[1][o] = bv;
    }

#define FMA4(p, wv, xs)                         \
    acc[p][ko * 4 + 0] += (wv).x * (xs);        \
    acc[p][ko * 4 + 1] += (wv).y * (xs);        \
    acc[p][ko * 4 + 2] += (wv).z * (xs);        \
    acc[p][ko * 4 + 3] += (wv).w * (xs);

    #pragma unroll
    for (int i = 0; i < CIN; ++i) {
        const float2 xv = *(const float2*)(xb + (size_t)i * N);  // coalesced 8B/lane
        #pragma unroll
        for (int ko = 0; ko < 4; ++ko) {
            const int base = i * 16 + ko * 4;   // compile-time per unrolled iter
            const float4 w0 = w4[base + sb0];   // ds_read_b128, broadcast-class
            const float4 w1 = w4[base + sb1];
            FMA4(0, w0, xv.x)
            FMA4(1, w1, xv.y)
        }
    }
#undef FMA4

    #pragma unroll
    for (int o = 0; o < COUT; ++o) {
        float2 r;
        r.x = acc[0][o]; r.y = acc[1][o];
        *(float2*)(ob + (size_t)o * N) = r;     // coalesced 8B/lane
    }
}

extern "C" void kernel_launch(void* const* d_in, const int* in_sizes, int n_in,
                              void* d_out, int out_size, void* d_ws, size_t ws_size,
                              hipStream_t stream) {
    const float* x    = (const float*)d_in[0];   // [B, CIN, N]
    const float* w    = (const float*)d_in[1];   // [COUT, CIN, SNUM, 1, 1]
    const float* bias = (const float*)d_in[2];   // [COUT]
    const int*   sidx = (const int*)d_in[3];     // [B, N]
    float* out = (float*)d_out;

    const int B = 2;
    const int N = in_sizes[3] / B;               // 2097152
    const int total_points = B * N;              // 4M, divisible by PPT*TPB
    const int nthreads = total_points / PPT;
    const int nblocks  = (nthreads + TPB - 1) / TPB;

    apr_conv1x1_kernel<<<nblocks, TPB, 0, stream>>>(x, w, bias, sidx, out, N);
}

// Round 6
// 458.310 us; speedup vs baseline: 1.5182x; 1.5182x over previous
//
#include <hip/hip_runtime.h>

#define CIN  16
#define COUT 16
#define SNUM 4
#define PPT  4    // points (n) per thread -> ALL global streams 16B/lane
#define TPB  256  // threads per block

typedef float  f32x4 __attribute__((ext_vector_type(4)));  // native clang vec
typedef int    i32x4 __attribute__((ext_vector_type(4)));

// out[b,o,n] = sum_i W[o,i,s(b,n)] * x[b,i,n] + bias[o]
//
// R1: PPT=4, full unroll -> VGPR=256, occ 10%, 2.2 TB/s, bytes ~0.46 GB -> 205us
// R3: PPT=2 (8B/lane)    -> VGPR=64,  occ 41%, 3.8 TB/s, bytes 1.49 GB (3.3x
//     amplification from sub-16B stores: partial-line evict + RFO) -> 388us
// R4/R5: PPT=4 (16B/lane streams, no amplification) + partial unroll + VGPR
//     cap so occupancy stays high. NT stores keep output from evicting x in L3.
__global__ __launch_bounds__(TPB, 4) void apr_conv1x1_kernel(
    const float* __restrict__ x,      // [B, CIN, N]
    const float* __restrict__ w,      // [COUT, CIN, SNUM]
    const float* __restrict__ bias,   // [COUT]
    const int*   __restrict__ sidx,   // [B, N]
    float*       __restrict__ out,    // [B, COUT, N]
    int N)
{
    // LDS weights, f32x4 index [i][ko][s]; elem j = W[o=ko*4+j][i][s].
    // Lane-varying address component is only s*16 B -> <=4 distinct
    // addresses/wave -> broadcast-class, conflict-free (R1/R3: 0 conflicts).
    __shared__ f32x4 w4[CIN * 4 * SNUM];   // 256 * 16B = 4 KiB

    const int t = threadIdx.x;
    {
        const int s  = t & 3;
        const int ko = (t >> 2) & 3;
        const int i  = t >> 4;
        f32x4 v;
        v.x = w[((ko * 4 + 0) * CIN + i) * SNUM + s];
        v.y = w[((ko * 4 + 1) * CIN + i) * SNUM + s];
        v.z = w[((ko * 4 + 2) * CIN + i) * SNUM + s];
        v.w = w[((ko * 4 + 3) * CIN + i) * SNUM + s];
        w4[t] = v;
    }
    __syncthreads();

    const unsigned tid  = blockIdx.x * TPB + t;
    const unsigned tpb_ = (unsigned)(N >> 2);         // threads per batch (PPT=4)
    const unsigned b    = (tid >= tpb_) ? 1u : 0u;    // B == 2: compare, no div
    const unsigned n    = (tid - b * tpb_) << 2;      // first of 4 consecutive n

    const float* xb = x   + (size_t)b * CIN  * N + n;
    float*       ob = out + (size_t)b * COUT * N + n;
    const i32x4 sv = *(const i32x4*)(sidx + (size_t)b * N + n);  // 16B/lane
    const int sb0 = sv.x, sb1 = sv.y, sb2 = sv.z, sb3 = sv.w;

    float acc[PPT][COUT];
    #pragma unroll
    for (int o = 0; o < COUT; ++o) {
        const float bv = bias[o];   // uniform address -> scalar load
        acc[0][o] = bv; acc[1][o] = bv; acc[2][o] = bv; acc[3][o] = bv;
    }

#define FMA4(p, wv, xs)                         \
    acc[p][ko * 4 + 0] += (wv).x * (xs);        \
    acc[p][ko * 4 + 1] += (wv).y * (xs);        \
    acc[p][ko * 4 + 2] += (wv).z * (xs);        \
    acc[p][ko * 4 + 3] += (wv).w * (xs);

    // Partial unroll: keeps the scheduler from clustering all 16 x-loads
    // (R1's 256-VGPR blowup) while still giving 4-deep load pipelining.
    #pragma unroll 4
    for (int i = 0; i < CIN; ++i) {
        const f32x4 xv = *(const f32x4*)(xb + (size_t)i * N);  // 16B/lane
        #pragma unroll
        for (int ko = 0; ko < 4; ++ko) {
            const int base = i * 16 + ko * 4;
            const f32x4 w0 = w4[base + sb0];   // ds_read_b128 broadcast
            const f32x4 w1 = w4[base + sb1];
            const f32x4 w2 = w4[base + sb2];
            const f32x4 w3 = w4[base + sb3];
            FMA4(0, w0, xv.x)
            FMA4(1, w1, xv.y)
            FMA4(2, w2, xv.z)
            FMA4(3, w3, xv.w)
        }
    }
#undef FMA4

    #pragma unroll
    for (int o = 0; o < COUT; ++o) {
        f32x4 r;
        r.x = acc[0][o]; r.y = acc[1][o]; r.z = acc[2][o]; r.w = acc[3][o];
        // NT: output is never re-read; don't let it evict x from L3.
        __builtin_nontemporal_store(r, (f32x4*)(ob + (size_t)o * N));
    }
}

extern "C" void kernel_launch(void* const* d_in, const int* in_sizes, int n_in,
                              void* d_out, int out_size, void* d_ws, size_t ws_size,
                              hipStream_t stream) {
    const float* x    = (const float*)d_in[0];   // [B, CIN, N]
    const float* w    = (const float*)d_in[1];   // [COUT, CIN, SNUM, 1, 1]
    const float* bias = (const float*)d_in[2];   // [COUT]
    const int*   sidx = (const int*)d_in[3];     // [B, N]
    float* out = (float*)d_out;

    const int B = 2;
    const int N = in_sizes[3] / B;               // 2097152
    const int total_points = B * N;              // 4M, divisible by PPT*TPB
    const int nthreads = total_points / PPT;
    const int nblocks  = (nthreads + TPB - 1) / TPB;

    apr_conv1x1_kernel<<<nblocks, TPB, 0, stream>>>(x, w, bias, sidx, out, N);
}